// Round 3
// baseline (92.619 us; speedup 1.0000x reference)
//
#include <hip/hip_runtime.h>
#include <math.h>

#define DDIM 200
#define CCH  50
#define NREL 237
#define G    4          // elements per group (share one W pass)
#define NT   256
#define WPB  (NT / 64)  // waves per block

// ---------- Kernel 1: counting sort by relation + group emission ----------
__global__ __launch_bounds__(1024) void relsort_kernel(
    const int* __restrict__ bi, int B, int ng_slots,
    int* __restrict__ perm, int* __restrict__ grp_r,
    int* __restrict__ grp_start, int* __restrict__ grp_cnt)
{
    __shared__ int hist[NREL];
    __shared__ int offs[NREL];
    __shared__ int goff[NREL];
    const int tid = threadIdx.x;
    for (int i = tid; i < NREL; i += 1024) hist[i] = 0;
    __syncthreads();
    for (int i = tid; i < B; i += 1024)
        atomicAdd(&hist[bi[i * 3 + 1]], 1);
    __syncthreads();
    if (tid == 0) {
        int acc = 0, gacc = 0;
        for (int r = 0; r < NREL; ++r) {
            offs[r] = acc;  acc  += hist[r];
            goff[r] = gacc; gacc += (hist[r] + G - 1) / G;
        }
    }
    __syncthreads();
    for (int i = tid; i < ng_slots; i += 1024) grp_cnt[i] = 0;
    if (tid < NREL) {
        const int n = hist[tid], base = offs[tid], gb = goff[tid];
        for (int k = 0, gi = 0; k < n; k += G, ++gi) {
            grp_r[gb + gi]     = tid;
            grp_start[gb + gi] = base + k;
            grp_cnt[gb + gi]   = min(G, n - k);
        }
    }
    __syncthreads();           // emission must finish before offs is mutated
    for (int i = tid; i < B; i += 1024) {
        int pos = atomicAdd(&offs[bi[i * 3 + 1]], 1);
        perm[pos] = i;
    }
}

// ---------- Kernel 2: one wave per group of G same-relation elements ----------
__global__ __launch_bounds__(NT) void spkbgat_main_kernel(
    const int*   __restrict__ bi,
    const float* __restrict__ ent,
    const float* __restrict__ rel_emb,
    const float* __restrict__ W,
    const float* __restrict__ conv_w,
    const float* __restrict__ conv_b,
    const float* __restrict__ fc_w,
    const float* __restrict__ fc_b,
    const int*   __restrict__ perm,
    const int*   __restrict__ grp_r,
    const int*   __restrict__ grp_start,
    const int*   __restrict__ grp_cnt,
    int nwg,
    float*       __restrict__ out)
{
    // s4/t4: staged as [d][g] for b128-broadcast matvec reads;
    //        reused post-matvec as [g][DDIM] (se/te) for lane-linear epilogue reads.
    __shared__ __align__(16) float s4[WPB][DDIM][G];
    __shared__ __align__(16) float t4[WPB][DDIM][G];
    __shared__ __align__(16) float rl[WPB][DDIM];
    __shared__ __align__(16) float cwb[CCH][4];   // {w0,w1,w2,b}

    const int tid  = threadIdx.x;
    const int w    = tid >> 6;
    const int lane = tid & 63;

    if (tid < CCH) {
        cwb[tid][0] = conv_w[tid * 3 + 0];
        cwb[tid][1] = conv_w[tid * 3 + 1];
        cwb[tid][2] = conv_w[tid * 3 + 2];
        cwb[tid][3] = conv_b[tid];
    }
    __syncthreads();   // only barrier; all threads reach it

    // bijective XCD-chunked swizzle: consecutive sorted groups -> same XCD
    const int bid = blockIdx.x;
    const int q = nwg >> 3, rmd = nwg & 7;
    const int xcd = bid & 7, idx = bid >> 3;
    const int swz = (xcd < rmd ? xcd * (q + 1) : rmd * (q + 1) + (xcd - rmd) * q) + idx;

    const int gidx = swz * WPB + w;
    const int cnt  = grp_cnt[gidx];
    if (cnt == 0) return;

    const int r     = grp_r[gidx];
    const int start = grp_start[gidx];

    int bg[G], hh[G], tt[G];
    #pragma unroll
    for (int g = 0; g < G; ++g) {
        if (g < cnt) {
            const int b = perm[start + g];
            bg[g] = b;
            hh[g] = bi[b * 3 + 0];
            tt[g] = bi[b * 3 + 2];
        } else { bg[g] = -1; hh[g] = 0; tt[g] = 0; }
    }

    // stage src/tail (transposed [d][g]) and rel
    for (int d = lane; d < DDIM; d += 64) {
        rl[w][d] = rel_emb[r * DDIM + d];
        #pragma unroll
        for (int g = 0; g < G; ++g) {
            s4[w][d][g] = (g < cnt) ? ent[hh[g] * DDIM + d] : 0.f;
            t4[w][d][g] = (g < cnt) ? ent[tt[g] * DDIM + d] : 0.f;
        }
    }

    // dual matvec x G: lane c (<50) owns output cols 4c..4c+3
    if (lane < CCH) {
        const float4* __restrict__ wp =
            (const float4*)(W + (size_t)r * (DDIM * DDIM)) + lane;
        float4 as[G], at[G];
        #pragma unroll
        for (int g = 0; g < G; ++g) { as[g] = float4{0,0,0,0}; at[g] = float4{0,0,0,0}; }

        #pragma unroll 8
        for (int d = 0; d < DDIM; ++d) {
            const float4 wv = wp[d * (DDIM / 4)];
            const float4 sv = *(const float4*)&s4[w][d][0];   // b128 broadcast
            const float4 tv = *(const float4*)&t4[w][d][0];
            const float sg[G] = {sv.x, sv.y, sv.z, sv.w};
            const float tg[G] = {tv.x, tv.y, tv.z, tv.w};
            #pragma unroll
            for (int g = 0; g < G; ++g) {
                as[g].x = fmaf(sg[g], wv.x, as[g].x);
                as[g].y = fmaf(sg[g], wv.y, as[g].y);
                as[g].z = fmaf(sg[g], wv.z, as[g].z);
                as[g].w = fmaf(sg[g], wv.w, as[g].w);
                at[g].x = fmaf(tg[g], wv.x, at[g].x);
                at[g].y = fmaf(tg[g], wv.y, at[g].y);
                at[g].z = fmaf(tg[g], wv.z, at[g].z);
                at[g].w = fmaf(tg[g], wv.w, at[g].w);
            }
        }
        // tanh, then repack LDS region as se[g][DDIM] / te[g][DDIM]
        float* seb = &s4[w][0][0];
        float* teb = &t4[w][0][0];
        #pragma unroll
        for (int g = 0; g < G; ++g) {
            const float4 se = {tanhf(as[g].x), tanhf(as[g].y), tanhf(as[g].z), tanhf(as[g].w)};
            const float4 te = {tanhf(at[g].x), tanhf(at[g].y), tanhf(at[g].z), tanhf(at[g].w)};
            *(float4*)&seb[g * DDIM + 4 * lane] = se;   // lane-linear, conflict-free
            *(float4*)&teb[g * DDIM + 4 * lane] = te;
        }
    }
    // same-wave LDS RAW: compiler inserts lgkmcnt waits; no barrier needed

    // fused conv+relu+fc: each fc float4 reused across all G elements
    const float* seb = &s4[w][0][0];
    const float* teb = &t4[w][0][0];
    float sum[G] = {0.f, 0.f, 0.f, 0.f};
    for (int task = lane; task < CCH * (DDIM / 4); task += 64) {
        const int c = task / (DDIM / 4);
        const int d = (task - c * (DDIM / 4)) * 4;
        const float4 cw = *(const float4*)&cwb[c][0];
        const float4 rv = *(const float4*)&rl[w][d];
        const float4 fv = *(const float4*)&fc_w[c * DDIM + d];   // L1/L2 cached
        #pragma unroll
        for (int g = 0; g < G; ++g) {
            const float4 sv = *(const float4*)&seb[g * DDIM + d];
            const float4 tv = *(const float4*)&teb[g * DDIM + d];
            const float v0 = fmaf(cw.x, sv.x, fmaf(cw.y, rv.x, fmaf(cw.z, tv.x, cw.w)));
            const float v1 = fmaf(cw.x, sv.y, fmaf(cw.y, rv.y, fmaf(cw.z, tv.y, cw.w)));
            const float v2 = fmaf(cw.x, sv.z, fmaf(cw.y, rv.z, fmaf(cw.z, tv.z, cw.w)));
            const float v3 = fmaf(cw.x, sv.w, fmaf(cw.y, rv.w, fmaf(cw.z, tv.w, cw.w)));
            sum[g] = fmaf(fmaxf(v0, 0.f), fv.x, sum[g]);
            sum[g] = fmaf(fmaxf(v1, 0.f), fv.y, sum[g]);
            sum[g] = fmaf(fmaxf(v2, 0.f), fv.z, sum[g]);
            sum[g] = fmaf(fmaxf(v3, 0.f), fv.w, sum[g]);
        }
    }

    #pragma unroll
    for (int g = 0; g < G; ++g)
        #pragma unroll
        for (int off = 32; off; off >>= 1)
            sum[g] += __shfl_down(sum[g], off, 64);

    if (lane == 0) {
        const float fb = fc_b[0];
        #pragma unroll
        for (int g = 0; g < G; ++g)
            if (g < cnt) out[bg[g]] = sum[g] + fb;
    }
}

extern "C" void kernel_launch(void* const* d_in, const int* in_sizes, int n_in,
                              void* d_out, int out_size, void* d_ws, size_t ws_size,
                              hipStream_t stream) {
    const int*   bi      = (const int*)  d_in[0];
    const float* ent     = (const float*)d_in[1];
    const float* rel_emb = (const float*)d_in[2];
    const float* W       = (const float*)d_in[3];
    const float* conv_w  = (const float*)d_in[4];
    const float* conv_b  = (const float*)d_in[5];
    const float* fc_w    = (const float*)d_in[6];
    const float* fc_b    = (const float*)d_in[7];
    float*       out     = (float*)d_out;

    const int B = in_sizes[0] / 3;                       // 8192
    int ng = NREL + (B + G - 1) / G;                     // max groups
    const int nwg = (ng + WPB - 1) / WPB;                // blocks
    const int ng_slots = nwg * WPB;

    int* perm      = (int*)d_ws;
    int* grp_r     = perm + B;
    int* grp_start = grp_r + ng_slots;
    int* grp_cnt   = grp_start + ng_slots;

    relsort_kernel<<<1, 1024, 0, stream>>>(bi, B, ng_slots, perm, grp_r, grp_start, grp_cnt);
    spkbgat_main_kernel<<<nwg, NT, 0, stream>>>(
        bi, ent, rel_emb, W, conv_w, conv_b, fc_w, fc_b,
        perm, grp_r, grp_start, grp_cnt, nwg, out);
}

// Round 4
// 71.376 us; speedup vs baseline: 1.2976x; 1.2976x over previous
//
#include <hip/hip_runtime.h>
#include <math.h>

#define DDIM 200
#define CCH  50
#define NREL 237
#define G    4          // elements per group (share one W pass)
#define NT   256
#define KS   (DDIM / 4) // K-slice per wave (50)
#define TPW  ((CCH * DDIM / 4) / 4)  // epilogue tasks per wave (625)

// ---------- Kernel 1: counting sort by relation + group emission ----------
__global__ __launch_bounds__(1024) void relsort_kernel(
    const int* __restrict__ bi, int B, int ng_slots,
    int* __restrict__ perm, int* __restrict__ grp_r,
    int* __restrict__ grp_start, int* __restrict__ grp_cnt)
{
    __shared__ int hist[NREL];
    __shared__ int offs[NREL];
    __shared__ int goff[NREL];
    __shared__ int wsum[16], wsum2[16];
    const int tid  = threadIdx.x;
    const int lane = tid & 63;
    const int w    = tid >> 6;

    if (tid < NREL) hist[tid] = 0;
    __syncthreads();
    for (int i = tid; i < B; i += 1024)
        atomicAdd(&hist[bi[i * 3 + 1]], 1);
    __syncthreads();

    // wave-parallel exclusive scans of hist and ceil(hist/G)
    {
        const int v  = (tid < NREL) ? hist[tid] : 0;
        const int v2 = (tid < NREL) ? (v + G - 1) / G : 0;
        int s = v, s2 = v2;
        #pragma unroll
        for (int off = 1; off < 64; off <<= 1) {
            const int u  = __shfl_up(s,  off, 64);
            const int u2 = __shfl_up(s2, off, 64);
            if (lane >= off) { s += u; s2 += u2; }
        }
        if (lane == 63) { wsum[w] = s; wsum2[w] = s2; }
        __syncthreads();
        if (tid < NREL) {
            int base = 0, base2 = 0;
            for (int i = 0; i < w; ++i) { base += wsum[i]; base2 += wsum2[i]; }
            offs[tid] = base + s - v;        // exclusive prefix
            goff[tid] = base2 + s2 - v2;
        }
    }
    __syncthreads();

    for (int i = tid; i < ng_slots; i += 1024) grp_cnt[i] = 0;
    if (tid < NREL) {
        const int n = hist[tid], base = offs[tid], gb = goff[tid];
        for (int k = 0, gi = 0; k < n; k += G, ++gi) {
            grp_r[gb + gi]     = tid;
            grp_start[gb + gi] = base + k;
            grp_cnt[gb + gi]   = min(G, n - k);
        }
    }
    __syncthreads();   // emission done before offs is mutated by scatter
    for (int i = tid; i < B; i += 1024) {
        const int pos = atomicAdd(&offs[bi[i * 3 + 1]], 1);
        perm[pos] = i;
    }
}

// ---------- Kernel 2: one block per group; 4 waves K-split the W pass ----------
__global__ __launch_bounds__(NT) void spkbgat_main_kernel(
    const int*   __restrict__ bi,
    const float* __restrict__ ent,
    const float* __restrict__ rel_emb,
    const float* __restrict__ W,
    const float* __restrict__ conv_w,
    const float* __restrict__ conv_b,
    const float* __restrict__ fc_w,
    const float* __restrict__ fc_b,
    const int*   __restrict__ perm,
    const int*   __restrict__ grp_r,
    const int*   __restrict__ grp_start,
    const int*   __restrict__ grp_cnt,
    int nwg,
    float*       __restrict__ out)
{
    __shared__ __align__(16) float s4[DDIM][G];        // [d][g] src staged
    __shared__ __align__(16) float t4[DDIM][G];        // [d][g] tail staged
    __shared__ __align__(16) float rl[DDIM];
    __shared__ __align__(16) float cwb[CCH][4];        // {w0,w1,w2,b}
    __shared__ __align__(16) float pt[4][2 * G][DDIM]; // [wave][vec][col] partials;
                                                       // pt[0] reused as se/te post-reduce
    __shared__ float red[4][G];

    const int tid  = threadIdx.x;
    const int w    = tid >> 6;
    const int lane = tid & 63;

    // bijective XCD-chunked swizzle: consecutive sorted groups -> same XCD
    const int bid = blockIdx.x;
    const int q = nwg >> 3, rmd = nwg & 7;
    const int xcd = bid & 7, idx = bid >> 3;
    const int gidx = (xcd < rmd ? xcd * (q + 1) : rmd * (q + 1) + (xcd - rmd) * q) + idx;

    const int cnt = grp_cnt[gidx];
    if (cnt == 0) return;   // block-uniform: safe before barriers

    const int r     = grp_r[gidx];
    const int start = grp_start[gidx];

    int bg[G], hh[G], tt[G];
    #pragma unroll
    for (int g = 0; g < G; ++g) {
        if (g < cnt) {
            const int b = perm[start + g];
            bg[g] = b;
            hh[g] = bi[b * 3 + 0];
            tt[g] = bi[b * 3 + 2];
        } else { bg[g] = -1; hh[g] = 0; tt[g] = 0; }
    }

    if (tid < CCH) {
        cwb[tid][0] = conv_w[tid * 3 + 0];
        cwb[tid][1] = conv_w[tid * 3 + 1];
        cwb[tid][2] = conv_w[tid * 3 + 2];
        cwb[tid][3] = conv_b[tid];
    }
    // stage rel + src/tail (transposed [d][g]); coalesced per vector
    for (int d = tid; d < DDIM; d += NT) rl[d] = rel_emb[r * DDIM + d];
    for (int i = tid; i < 2 * G * DDIM; i += NT) {
        const int vec = i / DDIM;          // 0..7
        const int d   = i - vec * DDIM;
        const int g   = vec & 3;
        const bool isT = vec >= G;
        const float val = (g < cnt) ? ent[(isT ? tt[g] : hh[g]) * DDIM + d] : 0.f;
        if (isT) t4[d][g] = val; else s4[d][g] = val;
    }
    __syncthreads();

    // Phase B: wave w covers d in [50w, 50w+50); lane c (<50) owns cols 4c..4c+3
    if (lane < CCH) {
        const float4* __restrict__ wp =
            (const float4*)(W + (size_t)r * (DDIM * DDIM)) + lane;
        float4 as[G], at[G];
        #pragma unroll
        for (int g = 0; g < G; ++g) { as[g] = float4{0,0,0,0}; at[g] = float4{0,0,0,0}; }
        const int d0 = w * KS;
        #pragma unroll 5
        for (int dd = 0; dd < KS; ++dd) {
            const int d = d0 + dd;
            const float4 wv = wp[d * (DDIM / 4)];             // coalesced L2 stream
            const float4 sv = *(const float4*)&s4[d][0];      // b128 broadcast
            const float4 tv = *(const float4*)&t4[d][0];
            const float sg[G] = {sv.x, sv.y, sv.z, sv.w};
            const float tg[G] = {tv.x, tv.y, tv.z, tv.w};
            #pragma unroll
            for (int g = 0; g < G; ++g) {
                as[g].x = fmaf(sg[g], wv.x, as[g].x);
                as[g].y = fmaf(sg[g], wv.y, as[g].y);
                as[g].z = fmaf(sg[g], wv.z, as[g].z);
                as[g].w = fmaf(sg[g], wv.w, as[g].w);
                at[g].x = fmaf(tg[g], wv.x, at[g].x);
                at[g].y = fmaf(tg[g], wv.y, at[g].y);
                at[g].z = fmaf(tg[g], wv.z, at[g].z);
                at[g].w = fmaf(tg[g], wv.w, at[g].w);
            }
        }
        #pragma unroll
        for (int g = 0; g < G; ++g) {
            *(float4*)&pt[w][g][4 * lane]     = as[g];   // consecutive 16B/lane
            *(float4*)&pt[w][G + g][4 * lane] = at[g];
        }
    }
    __syncthreads();

    // cross-wave K-reduce + tanh; result aliased into pt[0][vec][col]
    for (int i = tid; i < 2 * G * DDIM; i += NT) {
        const int vec = i / DDIM;
        const int col = i - vec * DDIM;
        const float v = pt[0][vec][col] + pt[1][vec][col]
                      + pt[2][vec][col] + pt[3][vec][col];
        pt[0][vec][col] = tanhf(v);
    }
    __syncthreads();

    // Epilogue: wave w owns task range [w*625,(w+1)*625); fc float4 reused over G
    float sum[G] = {0.f, 0.f, 0.f, 0.f};
    for (int task = w * TPW + lane; task < (w + 1) * TPW; task += 64) {
        const int c  = task / (DDIM / 4);
        const int d  = (task - c * (DDIM / 4)) * 4;
        const float4 cw = *(const float4*)&cwb[c][0];
        const float4 rv = *(const float4*)&rl[d];
        const float4 fv = *(const float4*)&fc_w[c * DDIM + d];
        #pragma unroll
        for (int g = 0; g < G; ++g) {
            const float4 sv = *(const float4*)&pt[0][g][d];
            const float4 tv = *(const float4*)&pt[0][G + g][d];
            const float v0 = fmaf(cw.x, sv.x, fmaf(cw.y, rv.x, fmaf(cw.z, tv.x, cw.w)));
            const float v1 = fmaf(cw.x, sv.y, fmaf(cw.y, rv.y, fmaf(cw.z, tv.y, cw.w)));
            const float v2 = fmaf(cw.x, sv.z, fmaf(cw.y, rv.z, fmaf(cw.z, tv.z, cw.w)));
            const float v3 = fmaf(cw.x, sv.w, fmaf(cw.y, rv.w, fmaf(cw.z, tv.w, cw.w)));
            sum[g] = fmaf(fmaxf(v0, 0.f), fv.x, sum[g]);
            sum[g] = fmaf(fmaxf(v1, 0.f), fv.y, sum[g]);
            sum[g] = fmaf(fmaxf(v2, 0.f), fv.z, sum[g]);
            sum[g] = fmaf(fmaxf(v3, 0.f), fv.w, sum[g]);
        }
    }
    #pragma unroll
    for (int g = 0; g < G; ++g)
        #pragma unroll
        for (int off = 32; off; off >>= 1)
            sum[g] += __shfl_down(sum[g], off, 64);
    if (lane == 0) {
        #pragma unroll
        for (int g = 0; g < G; ++g) red[w][g] = sum[g];
    }
    __syncthreads();
    if (tid < G && tid < cnt) {
        out[bg[tid]] = red[0][tid] + red[1][tid] + red[2][tid] + red[3][tid] + fc_b[0];
    }
}

extern "C" void kernel_launch(void* const* d_in, const int* in_sizes, int n_in,
                              void* d_out, int out_size, void* d_ws, size_t ws_size,
                              hipStream_t stream) {
    const int*   bi      = (const int*)  d_in[0];
    const float* ent     = (const float*)d_in[1];
    const float* rel_emb = (const float*)d_in[2];
    const float* W       = (const float*)d_in[3];
    const float* conv_w  = (const float*)d_in[4];
    const float* conv_b  = (const float*)d_in[5];
    const float* fc_w    = (const float*)d_in[6];
    const float* fc_b    = (const float*)d_in[7];
    float*       out     = (float*)d_out;

    const int B   = in_sizes[0] / 3;                 // 8192
    const int nwg = NREL + (B + G - 1) / G;          // max groups = blocks

    int* perm      = (int*)d_ws;
    int* grp_r     = perm + B;
    int* grp_start = grp_r + nwg;
    int* grp_cnt   = grp_start + nwg;

    relsort_kernel<<<1, 1024, 0, stream>>>(bi, B, nwg, perm, grp_r, grp_start, grp_cnt);
    spkbgat_main_kernel<<<nwg, NT, 0, stream>>>(
        bi, ent, rel_emb, W, conv_w, conv_b, fc_w, fc_b,
        perm, grp_r, grp_start, grp_cnt, nwg, out);
}